// Round 13
// baseline (413.280 us; speedup 1.0000x reference)
//
#include <hip/hip_runtime.h>

#define CB 256        // chunk-blocks for hist/scatter
#define MAXNB 1024    // max buckets (N <= 262144)

// ---------------- bucket-sort CSR build (no global atomics) ----------------

__global__ void k_hist(const int* __restrict__ dst, int* __restrict__ histG,
                       int E, int NB, int chunk) {
  __shared__ int hist[MAXNB];
  int b = blockIdx.x, tid = threadIdx.x;
  for (int k = tid; k < NB; k += 256) hist[k] = 0;
  __syncthreads();
  int beg = b * chunk, end = min(E, beg + chunk);
  int nvec = (end - beg) & ~3;
  for (int i = beg + tid * 4; i < beg + nvec; i += 1024) {
    int4 d = *(const int4*)(dst + i);
    atomicAdd(&hist[d.x >> 8], 1); atomicAdd(&hist[d.y >> 8], 1);
    atomicAdd(&hist[d.z >> 8], 1); atomicAdd(&hist[d.w >> 8], 1);
  }
  for (int i = beg + nvec + tid; i < end; i += 256) atomicAdd(&hist[dst[i] >> 8], 1);
  __syncthreads();
  for (int k = tid; k < NB; k += 256) histG[(size_t)k * CB + b] = hist[k];
}

__global__ void k_scan_local(const int* __restrict__ in, int* __restrict__ out,
                             int* __restrict__ blockSums, int n) {
  __shared__ int wsum[16];
  __shared__ int wpre[16];
  int tid = threadIdx.x;
  int gid = blockIdx.x * 1024 + tid;
  int v = (gid < n) ? in[gid] : 0;
  int lane = tid & 63, wv = tid >> 6;
  int x = v;
#pragma unroll
  for (int d = 1; d < 64; d <<= 1) {
    int t = __shfl_up(x, d);
    if (lane >= d) x += t;
  }
  if (lane == 63) wsum[wv] = x;
  __syncthreads();
  if (tid == 0) {
    int run = 0;
#pragma unroll
    for (int i = 0; i < 16; ++i) { wpre[i] = run; run += wsum[i]; }
    blockSums[blockIdx.x] = run;
  }
  __syncthreads();
  if (gid < n) out[gid] = x - v + wpre[wv];
}

// parallel scan of block sums (single block, 256 threads, nb <= 256)
__global__ void k_scan_blocks(const int* __restrict__ blockSums, int* __restrict__ blockOffs, int nb) {
  __shared__ int wtot[4];
  int tid = threadIdx.x;
  int lane = tid & 63, w = tid >> 6;
  int v = (tid < nb) ? blockSums[tid] : 0;
  int x = v;
#pragma unroll
  for (int d = 1; d < 64; d <<= 1) {
    int t = __shfl_up(x, d);
    if (lane >= d) x += t;
  }
  if (lane == 63) wtot[w] = x;
  __syncthreads();
  int pre = 0;
  for (int i = 0; i < w; ++i) pre += wtot[i];
  int ex = x - v + pre;
  if (tid < nb) blockOffs[tid] = ex;
  if (tid == nb - 1) blockOffs[nb] = ex + v;
}

__global__ void k_scatter(const int* __restrict__ src, const int* __restrict__ dst,
                          const int* __restrict__ histS, const int* __restrict__ blockOffs,
                          unsigned* __restrict__ recs, int E, int NB, int chunk) {
  __shared__ int cur[MAXNB];
  int b = blockIdx.x, tid = threadIdx.x;
  for (int k = tid; k < NB; k += 256) {
    int gid = k * CB + b;
    cur[k] = histS[gid] + blockOffs[gid >> 10];
  }
  __syncthreads();
  int beg = b * chunk, end = min(E, beg + chunk);
  int nvec = (end - beg) & ~3;
  for (int i = beg + tid * 4; i < beg + nvec; i += 1024) {
    int4 s4 = *(const int4*)(src + i);
    int4 d4 = *(const int4*)(dst + i);
    int p0 = atomicAdd(&cur[d4.x >> 8], 1);
    recs[p0] = ((unsigned)s4.x << 8) | (unsigned)(d4.x & 255);
    int p1 = atomicAdd(&cur[d4.y >> 8], 1);
    recs[p1] = ((unsigned)s4.y << 8) | (unsigned)(d4.y & 255);
    int p2 = atomicAdd(&cur[d4.z >> 8], 1);
    recs[p2] = ((unsigned)s4.z << 8) | (unsigned)(d4.z & 255);
    int p3 = atomicAdd(&cur[d4.w >> 8], 1);
    recs[p3] = ((unsigned)s4.w << 8) | (unsigned)(d4.w & 255);
  }
  for (int i = beg + nvec + tid; i < end; i += 256) {
    int s = src[i], d = dst[i];
    int pos = atomicAdd(&cur[d >> 8], 1);
    recs[pos] = ((unsigned)s << 8) | (unsigned)(d & 255);
  }
}

// per-bucket CSR finalize; also writes inv_sqrt and prescaled xp = x * inv_sqrt
__global__ void k_build(const unsigned* __restrict__ recs, const int* __restrict__ histS,
                        const int* __restrict__ blockOffs, const float* __restrict__ x,
                        int* __restrict__ offs, float* __restrict__ inv_sqrt,
                        float* __restrict__ xp, int* __restrict__ srcs,
                        int N, int NB, int E) {
  __shared__ int cnt[256];
  __shared__ int cur[256];
  __shared__ int wtot[4];
  int k = blockIdx.x, tid = threadIdx.x;
  int g0 = k * CB;
  int ebeg = histS[g0] + blockOffs[g0 >> 10];
  int eend = E;
  if (k + 1 < NB) {
    int g1 = (k + 1) * CB;
    eend = histS[g1] + blockOffs[g1 >> 10];
  }
  cnt[tid] = 0;
  __syncthreads();
  int nvec = (eend - ebeg) & ~3;
  for (int i = ebeg + tid * 4; i < ebeg + nvec; i += 1024) {
    uint4 r = *(const uint4*)(recs + i);
    atomicAdd(&cnt[r.x & 255u], 1); atomicAdd(&cnt[r.y & 255u], 1);
    atomicAdd(&cnt[r.z & 255u], 1); atomicAdd(&cnt[r.w & 255u], 1);
  }
  for (int i = ebeg + nvec + tid; i < eend; i += 256) atomicAdd(&cnt[recs[i] & 255u], 1);
  __syncthreads();
  int v = cnt[tid];
  int lane = tid & 63, w = tid >> 6;
  int x_ = v;
#pragma unroll
  for (int d = 1; d < 64; d <<= 1) {
    int t = __shfl_up(x_, d);
    if (lane >= d) x_ += t;
  }
  if (lane == 63) wtot[w] = x_;
  __syncthreads();
  int pre = 0;
  for (int i = 0; i < w; ++i) pre += wtot[i];
  int gpos = ebeg + (x_ - v) + pre;
  int node = k * 256 + tid;
  if (node < N) {
    offs[node] = gpos;
    float is = rsqrtf(1.0f + (float)v);
    inv_sqrt[node] = is;
    const float* xr = x + (size_t)node * 5;
    float* xo = xp + (size_t)node * 5;
    xo[0] = xr[0] * is; xo[1] = xr[1] * is; xo[2] = xr[2] * is;
    xo[3] = xr[3] * is; xo[4] = xr[4] * is;
  }
  cur[tid] = gpos;
  if (k == NB - 1 && tid == 0) offs[N] = E;
  __syncthreads();
  for (int i = ebeg + tid * 4; i < ebeg + nvec; i += 1024) {
    uint4 r = *(const uint4*)(recs + i);
    int p0 = atomicAdd(&cur[r.x & 255u], 1); srcs[p0] = (int)(r.x >> 8);
    int p1 = atomicAdd(&cur[r.y & 255u], 1); srcs[p1] = (int)(r.y >> 8);
    int p2 = atomicAdd(&cur[r.z & 255u], 1); srcs[p2] = (int)(r.z >> 8);
    int p3 = atomicAdd(&cur[r.w & 255u], 1); srcs[p3] = (int)(r.w >> 8);
  }
  for (int i = ebeg + nvec + tid; i < eend; i += 256) {
    unsigned r = recs[i];
    int pos = atomicAdd(&cur[r & 255u], 1);
    srcs[pos] = (int)(r >> 8);
  }
}

// ---------------- layer kernels ----------------

// layers 1+2a fused, 2 nodes/wave (r10-proven: compiler keeps wreg[64] in VGPRs here).
// Output SLICED + prescaled: hS[slice][node][8] = (relu((A x)W1+b1) @ W2) * inv_sqrt[node]
__global__ void k_l12(const float* __restrict__ xp, const int* __restrict__ offs,
                      const int* __restrict__ srcs, const float* __restrict__ inv_sqrt,
                      const float* __restrict__ W1, const float* __restrict__ b1,
                      const float* __restrict__ W2, float* __restrict__ hS, int n) {
  __shared__ float hrow[4][2][64];
  int tid = threadIdx.x;
  int lane = tid & 63, w = tid >> 6;
  int hl = lane & 31, half = lane >> 5;
  int slice = lane >> 3, feat = lane & 7;
  float w1r[5];
#pragma unroll
  for (int k = 0; k < 5; ++k) w1r[k] = W1[k * 64 + lane];
  float bias = b1[lane];
  float wreg[64];
#pragma unroll
  for (int k = 0; k < 64; ++k) wreg[k] = W2[k * 64 + lane];
  float* slotA = &hrow[w][0][0];
  float* slotB = &hrow[w][1][0];
  int wid0 = (blockIdx.x * blockDim.x + tid) >> 6;
  int nw = (gridDim.x * blockDim.x) >> 6;
  for (int i2 = wid0 * 2; i2 < n; i2 += nw * 2) {
    int iA = i2, iB = i2 + 1;
    int node = (half == 0) ? iA : iB;
    bool valid = node < n;
    float a0 = 0.f, a1 = 0.f, a2 = 0.f, a3 = 0.f, a4 = 0.f;
    float isd = 0.f;
    if (valid) {
      isd = inv_sqrt[node];
      int beg = offs[node], end = offs[node + 1];
      for (int j = beg + hl; j < end; j += 32) {
        int s = srcs[j];
        const float* xs = xp + (size_t)s * 5;
        float4 xv = *(const float4*)xs;   // 4B-aligned dwordx4 (HW-legal)
        float x4 = xs[4];
        a0 += xv.x; a1 += xv.y; a2 += xv.z; a3 += xv.w; a4 += x4;
      }
    }
#pragma unroll
    for (int d = 16; d; d >>= 1) {
      a0 += __shfl_xor(a0, d); a1 += __shfl_xor(a1, d); a2 += __shfl_xor(a2, d);
      a3 += __shfl_xor(a3, d); a4 += __shfl_xor(a4, d);
    }
    if (valid) {
      const float* xi = xp + (size_t)node * 5;
      a0 = (a0 + xi[0]) * isd; a1 = (a1 + xi[1]) * isd; a2 = (a2 + xi[2]) * isd;
      a3 = (a3 + xi[3]) * isd; a4 = (a4 + xi[4]) * isd;
    }
    float aA0 = __shfl(a0, hl),      aA1 = __shfl(a1, hl),      aA2 = __shfl(a2, hl);
    float aA3 = __shfl(a3, hl),      aA4 = __shfl(a4, hl);
    float aB0 = __shfl(a0, hl | 32), aB1 = __shfl(a1, hl | 32), aB2 = __shfl(a2, hl | 32);
    float aB3 = __shfl(a3, hl | 32), aB4 = __shfl(a4, hl | 32);
    float isdA = __shfl(isd, 0), isdB = __shfl(isd, 32);
    float hA = bias;
    hA = fmaf(aA0, w1r[0], hA); hA = fmaf(aA1, w1r[1], hA); hA = fmaf(aA2, w1r[2], hA);
    hA = fmaf(aA3, w1r[3], hA); hA = fmaf(aA4, w1r[4], hA);
    hA = fmaxf(hA, 0.f);
    float hB = bias;
    hB = fmaf(aB0, w1r[0], hB); hB = fmaf(aB1, w1r[1], hB); hB = fmaf(aB2, w1r[2], hB);
    hB = fmaf(aB3, w1r[3], hB); hB = fmaf(aB4, w1r[4], hB);
    hB = fmaxf(hB, 0.f);
    slotA[lane] = hA;
    slotB[lane] = hB;
    float ac0 = 0.f, ac1 = 0.f, ac2 = 0.f, ac3 = 0.f;
#pragma unroll
    for (int k4 = 0; k4 < 16; ++k4) {
      float4 hq = *(const float4*)&slotA[k4 * 4];
      ac0 = fmaf(hq.x, wreg[k4 * 4],     ac0);
      ac1 = fmaf(hq.y, wreg[k4 * 4 + 1], ac1);
      ac2 = fmaf(hq.z, wreg[k4 * 4 + 2], ac2);
      ac3 = fmaf(hq.w, wreg[k4 * 4 + 3], ac3);
    }
    hS[((size_t)slice * n + iA) * 8 + feat] = ((ac0 + ac1) + (ac2 + ac3)) * isdA;
    if (iB < n) {
      float bc0 = 0.f, bc1 = 0.f, bc2 = 0.f, bc3 = 0.f;
#pragma unroll
      for (int k4 = 0; k4 < 16; ++k4) {
        float4 hq = *(const float4*)&slotB[k4 * 4];
        bc0 = fmaf(hq.x, wreg[k4 * 4],     bc0);
        bc1 = fmaf(hq.y, wreg[k4 * 4 + 1], bc1);
        bc2 = fmaf(hq.z, wreg[k4 * 4 + 2], bc2);
        bc3 = fmaf(hq.w, wreg[k4 * 4 + 3], bc3);
      }
      hS[((size_t)slice * n + iB) * 8 + feat] = ((bc0 + bc1) + (bc2 + bc3)) * isdB;
    }
  }
}

// sliced aggregation v2: slice = blockIdx&7 -> XCD-pinned 3.2MB L2-resident strip.
// lane = (slot 0..7, feat 0..7); each slot owns a CONTIGUOUS run of 4 edges
// (one int4 index load + 4x32B row loads) -> 32 edges in flight per wave.
// Epilogue: 3 shfl + self + one 32B store of RAW partials (no W3/isd here).
__global__ void k_aggS(const float* __restrict__ hS, const int* __restrict__ offs,
                       const int* __restrict__ srcs, float* __restrict__ h2agg, int n) {
  int slice = blockIdx.x & 7;
  int tid = threadIdx.x;
  int lane = tid & 63;
  int slot = lane >> 3, feat = lane & 7;
  const float* hbase = hS + (size_t)slice * n * 8;
  int wid0 = ((blockIdx.x >> 3) << 2) + (tid >> 6);   // 4 waves/block
  int nw = (gridDim.x >> 3) << 2;
  for (int i = wid0; i < n; i += nw) {
    int beg = offs[i], end = offs[i + 1];
    float a0 = 0.f, a1 = 0.f, a2 = 0.f, a3 = 0.f;
    int c = beg;
    for (; c + 32 <= end; c += 32) {
      int j = c + (slot << 2);
      int4 sv = *(const int4*)(srcs + j);
      a0 += hbase[(size_t)sv.x * 8 + feat];
      a1 += hbase[(size_t)sv.y * 8 + feat];
      a2 += hbase[(size_t)sv.z * 8 + feat];
      a3 += hbase[(size_t)sv.w * 8 + feat];
    }
    int j0 = c + (slot << 2);
    int je = min(j0 + 4, end);
    for (int j = j0; j < je; ++j) a0 += hbase[(size_t)srcs[j] * 8 + feat];
    float acc = (a0 + a1) + (a2 + a3);
    acc += __shfl_xor(acc, 8);
    acc += __shfl_xor(acc, 16);
    acc += __shfl_xor(acc, 32);
    acc += hbase[(size_t)i * 8 + feat];   // self row (prescaled)
    if (slot == 0) h2agg[(size_t)i * 64 + slice * 8 + feat] = acc;
  }
}

// finalize: h2 = relu(isd*agg + b2); h3p = (h2 @ W3) * isd   (streaming, 1 wave/node)
__global__ void k_fin(const float* __restrict__ h2agg, const float* __restrict__ inv_sqrt,
                      const float* __restrict__ b2, const float* __restrict__ W3,
                      float* __restrict__ h3p, int n) {
  int lane = threadIdx.x & 63;
  float b2v = b2[lane];
  float w30 = W3[lane * 2], w31 = W3[lane * 2 + 1];
  int wid0 = (blockIdx.x * blockDim.x + threadIdx.x) >> 6;
  int nw = (gridDim.x * blockDim.x) >> 6;
  for (int i = wid0; i < n; i += nw) {
    float isd = inv_sqrt[i];
    float agg = h2agg[(size_t)i * 64 + lane];
    float h2 = fmaxf(fmaf(isd, agg, b2v), 0.f);
    float p0 = h2 * w30, p1 = h2 * w31;
#pragma unroll
    for (int d = 32; d; d >>= 1) { p0 += __shfl_xor(p0, d); p1 += __shfl_xor(p1, d); }
    if (lane == 0) {
      h3p[(size_t)i * 2]     = p0 * isd;
      h3p[(size_t)i * 2 + 1] = p1 * isd;
    }
  }
}

// out = isd*(sum h3p[src] + h3p[self]) + b3  — TWO nodes per wave (32-lane halves)
__global__ void k_agg2(const float* __restrict__ h3p, const int* __restrict__ offs,
                       const int* __restrict__ srcs, const float* __restrict__ inv_sqrt,
                       const float* __restrict__ b3, float* __restrict__ out, int n) {
  int wv = (blockIdx.x * blockDim.x + threadIdx.x) >> 6;
  int lane = threadIdx.x & 63;
  int half = lane >> 5, hl = lane & 31;
  int node = wv * 2 + half;
  float a0 = 0.f, a1 = 0.f;
  if (node < n) {
    int beg = offs[node], end = offs[node + 1];
    for (int j = beg + hl; j < end; j += 32) {
      int s = srcs[j];
      float2 hv = *(const float2*)(h3p + (size_t)s * 2);
      a0 += hv.x; a1 += hv.y;
    }
  }
#pragma unroll
  for (int d = 16; d; d >>= 1) { a0 += __shfl_xor(a0, d); a1 += __shfl_xor(a1, d); }
  if (node < n && hl == 0) {
    float isd = inv_sqrt[node];
    float2 self = *(const float2*)(h3p + (size_t)node * 2);
    out[(size_t)node * 2]     = fmaf(isd, a0 + self.x, b3[0]);
    out[(size_t)node * 2 + 1] = fmaf(isd, a1 + self.y, b3[1]);
  }
}

// ---------------- launcher ----------------

extern "C" void kernel_launch(void* const* d_in, const int* in_sizes, int n_in,
                              void* d_out, int out_size, void* d_ws, size_t ws_size,
                              hipStream_t stream) {
  const float* x  = (const float*)d_in[0];
  const int*   ei = (const int*)d_in[1];
  const float* W1 = (const float*)d_in[2];
  const float* b1 = (const float*)d_in[3];
  const float* W2 = (const float*)d_in[4];
  const float* b2 = (const float*)d_in[5];
  const float* W3 = (const float*)d_in[6];
  const float* b3 = (const float*)d_in[7];
  float* out = (float*)d_out;

  const int N = in_sizes[0] / 5;
  const int E = in_sizes[1] / 2;
  const int* src = ei;
  const int* dst = ei + E;

  const int NB = (N + 255) >> 8;
  const int chunk = (E + CB - 1) / CB;
  const int n2 = NB * CB;
  const int nb2 = (n2 + 1023) / 1024;   // <= 256

  char* p = (char*)d_ws;
  auto alloc = [&](size_t bytes) {
    char* r = p;
    p += (bytes + 255) & ~(size_t)255;
    return r;
  };
  int*      histG     = (int*)alloc((size_t)n2 * 4);
  int*      histS     = (int*)alloc((size_t)n2 * 4);
  int*      blockSums = (int*)alloc((size_t)nb2 * 4);
  int*      blockOffs = (int*)alloc((size_t)(nb2 + 1) * 4);
  unsigned* recs      = (unsigned*)alloc((size_t)E * 4);
  int*      srcs      = (int*)alloc((size_t)E * 4);
  int*      offs      = (int*)alloc((size_t)(N + 1) * 4);
  float*    inv_sqrt  = (float*)alloc((size_t)N * 4);
  float*    xp        = (float*)alloc((size_t)N * 5 * 4);
  float*    hS        = (float*)alloc((size_t)N * 64 * 4);
  float*    h2agg     = (float*)alloc((size_t)N * 64 * 4);
  float*    h3p       = (float*)alloc((size_t)N * 2 * 4);

  const int pairs = (N + 1) / 2;
  const int pairBlocks = (pairs * 64 + 255) / 256;    // one wave per 2 nodes

  // CSR build via stable bucket sort — zero global atomics
  k_hist<<<CB, 256, 0, stream>>>(dst, histG, E, NB, chunk);
  k_scan_local<<<nb2, 1024, 0, stream>>>(histG, histS, blockSums, n2);
  k_scan_blocks<<<1, 256, 0, stream>>>(blockSums, blockOffs, nb2);
  k_scatter<<<CB, 256, 0, stream>>>(src, dst, histS, blockOffs, recs, E, NB, chunk);
  k_build<<<NB, 256, 0, stream>>>(recs, histS, blockOffs, x, offs, inv_sqrt, xp, srcs, N, NB, E);

  // layers 1+2a fused: hS[slice][node][8] = (relu((A x) W1 + b1) @ W2) * inv_sqrt
  k_l12<<<2048, 256, 0, stream>>>(xp, offs, srcs, inv_sqrt, W1, b1, W2, hS, N);
  // layer 2b: XCD-sliced gather of raw partials
  k_aggS<<<2048, 256, 0, stream>>>(hS, offs, srcs, h2agg, N);
  // layer 2c+3a: relu/b2/W3 finalize (streaming)
  k_fin<<<2048, 256, 0, stream>>>(h2agg, inv_sqrt, b2, W3, h3p, N);
  // layer 3 aggregation (2 nodes/wave)
  k_agg2<<<pairBlocks, 256, 0, stream>>>(h3p, offs, srcs, inv_sqrt, b3, out, N);
}

// Round 14
// 225.270 us; speedup vs baseline: 1.8346x; 1.8346x over previous
//
#include <hip/hip_runtime.h>
#include <hip/hip_fp16.h>

#define CB 256        // chunk-blocks for hist/scatter
#define MAXNB 1024    // max buckets (N <= 262144)

// ---------------- bucket-sort CSR build (no global atomics) ----------------

__global__ void k_hist(const int* __restrict__ dst, int* __restrict__ histG,
                       int E, int NB, int chunk) {
  __shared__ int hist[MAXNB];
  int b = blockIdx.x, tid = threadIdx.x;
  for (int k = tid; k < NB; k += 256) hist[k] = 0;
  __syncthreads();
  int beg = b * chunk, end = min(E, beg + chunk);
  int nvec = (end - beg) & ~3;
  for (int i = beg + tid * 4; i < beg + nvec; i += 1024) {
    int4 d = *(const int4*)(dst + i);
    atomicAdd(&hist[d.x >> 8], 1); atomicAdd(&hist[d.y >> 8], 1);
    atomicAdd(&hist[d.z >> 8], 1); atomicAdd(&hist[d.w >> 8], 1);
  }
  for (int i = beg + nvec + tid; i < end; i += 256) atomicAdd(&hist[dst[i] >> 8], 1);
  __syncthreads();
  for (int k = tid; k < NB; k += 256) histG[(size_t)k * CB + b] = hist[k];
}

__global__ void k_scan_local(const int* __restrict__ in, int* __restrict__ out,
                             int* __restrict__ blockSums, int n) {
  __shared__ int wsum[16];
  __shared__ int wpre[16];
  int tid = threadIdx.x;
  int gid = blockIdx.x * 1024 + tid;
  int v = (gid < n) ? in[gid] : 0;
  int lane = tid & 63, wv = tid >> 6;
  int x = v;
#pragma unroll
  for (int d = 1; d < 64; d <<= 1) {
    int t = __shfl_up(x, d);
    if (lane >= d) x += t;
  }
  if (lane == 63) wsum[wv] = x;
  __syncthreads();
  if (tid == 0) {
    int run = 0;
#pragma unroll
    for (int i = 0; i < 16; ++i) { wpre[i] = run; run += wsum[i]; }
    blockSums[blockIdx.x] = run;
  }
  __syncthreads();
  if (gid < n) out[gid] = x - v + wpre[wv];
}

// parallel scan of block sums (single block, 256 threads, nb <= 256)
__global__ void k_scan_blocks(const int* __restrict__ blockSums, int* __restrict__ blockOffs, int nb) {
  __shared__ int wtot[4];
  int tid = threadIdx.x;
  int lane = tid & 63, w = tid >> 6;
  int v = (tid < nb) ? blockSums[tid] : 0;
  int x = v;
#pragma unroll
  for (int d = 1; d < 64; d <<= 1) {
    int t = __shfl_up(x, d);
    if (lane >= d) x += t;
  }
  if (lane == 63) wtot[w] = x;
  __syncthreads();
  int pre = 0;
  for (int i = 0; i < w; ++i) pre += wtot[i];
  int ex = x - v + pre;
  if (tid < nb) blockOffs[tid] = ex;
  if (tid == nb - 1) blockOffs[nb] = ex + v;
}

__global__ void k_scatter(const int* __restrict__ src, const int* __restrict__ dst,
                          const int* __restrict__ histS, const int* __restrict__ blockOffs,
                          unsigned* __restrict__ recs, int E, int NB, int chunk) {
  __shared__ int cur[MAXNB];
  int b = blockIdx.x, tid = threadIdx.x;
  for (int k = tid; k < NB; k += 256) {
    int gid = k * CB + b;
    cur[k] = histS[gid] + blockOffs[gid >> 10];
  }
  __syncthreads();
  int beg = b * chunk, end = min(E, beg + chunk);
  int nvec = (end - beg) & ~3;
  for (int i = beg + tid * 4; i < beg + nvec; i += 1024) {
    int4 s4 = *(const int4*)(src + i);
    int4 d4 = *(const int4*)(dst + i);
    int p0 = atomicAdd(&cur[d4.x >> 8], 1);
    recs[p0] = ((unsigned)s4.x << 8) | (unsigned)(d4.x & 255);
    int p1 = atomicAdd(&cur[d4.y >> 8], 1);
    recs[p1] = ((unsigned)s4.y << 8) | (unsigned)(d4.y & 255);
    int p2 = atomicAdd(&cur[d4.z >> 8], 1);
    recs[p2] = ((unsigned)s4.z << 8) | (unsigned)(d4.z & 255);
    int p3 = atomicAdd(&cur[d4.w >> 8], 1);
    recs[p3] = ((unsigned)s4.w << 8) | (unsigned)(d4.w & 255);
  }
  for (int i = beg + nvec + tid; i < end; i += 256) {
    int s = src[i], d = dst[i];
    int pos = atomicAdd(&cur[d >> 8], 1);
    recs[pos] = ((unsigned)s << 8) | (unsigned)(d & 255);
  }
}

// per-bucket CSR finalize; also writes inv_sqrt and prescaled xp = x * inv_sqrt
__global__ void k_build(const unsigned* __restrict__ recs, const int* __restrict__ histS,
                        const int* __restrict__ blockOffs, const float* __restrict__ x,
                        int* __restrict__ offs, float* __restrict__ inv_sqrt,
                        float* __restrict__ xp, int* __restrict__ srcs,
                        int N, int NB, int E) {
  __shared__ int cnt[256];
  __shared__ int cur[256];
  __shared__ int wtot[4];
  int k = blockIdx.x, tid = threadIdx.x;
  int g0 = k * CB;
  int ebeg = histS[g0] + blockOffs[g0 >> 10];
  int eend = E;
  if (k + 1 < NB) {
    int g1 = (k + 1) * CB;
    eend = histS[g1] + blockOffs[g1 >> 10];
  }
  cnt[tid] = 0;
  __syncthreads();
  int nvec = (eend - ebeg) & ~3;
  for (int i = ebeg + tid * 4; i < ebeg + nvec; i += 1024) {
    uint4 r = *(const uint4*)(recs + i);
    atomicAdd(&cnt[r.x & 255u], 1); atomicAdd(&cnt[r.y & 255u], 1);
    atomicAdd(&cnt[r.z & 255u], 1); atomicAdd(&cnt[r.w & 255u], 1);
  }
  for (int i = ebeg + nvec + tid; i < eend; i += 256) atomicAdd(&cnt[recs[i] & 255u], 1);
  __syncthreads();
  int v = cnt[tid];
  int lane = tid & 63, w = tid >> 6;
  int x_ = v;
#pragma unroll
  for (int d = 1; d < 64; d <<= 1) {
    int t = __shfl_up(x_, d);
    if (lane >= d) x_ += t;
  }
  if (lane == 63) wtot[w] = x_;
  __syncthreads();
  int pre = 0;
  for (int i = 0; i < w; ++i) pre += wtot[i];
  int gpos = ebeg + (x_ - v) + pre;
  int node = k * 256 + tid;
  if (node < N) {
    offs[node] = gpos;
    float is = rsqrtf(1.0f + (float)v);
    inv_sqrt[node] = is;
    const float* xr = x + (size_t)node * 5;
    float* xo = xp + (size_t)node * 5;
    xo[0] = xr[0] * is; xo[1] = xr[1] * is; xo[2] = xr[2] * is;
    xo[3] = xr[3] * is; xo[4] = xr[4] * is;
  }
  cur[tid] = gpos;
  if (k == NB - 1 && tid == 0) offs[N] = E;
  __syncthreads();
  for (int i = ebeg + tid * 4; i < ebeg + nvec; i += 1024) {
    uint4 r = *(const uint4*)(recs + i);
    int p0 = atomicAdd(&cur[r.x & 255u], 1); srcs[p0] = (int)(r.x >> 8);
    int p1 = atomicAdd(&cur[r.y & 255u], 1); srcs[p1] = (int)(r.y >> 8);
    int p2 = atomicAdd(&cur[r.z & 255u], 1); srcs[p2] = (int)(r.z >> 8);
    int p3 = atomicAdd(&cur[r.w & 255u], 1); srcs[p3] = (int)(r.w >> 8);
  }
  for (int i = ebeg + nvec + tid; i < eend; i += 256) {
    unsigned r = recs[i];
    int pos = atomicAdd(&cur[r & 255u], 1);
    srcs[pos] = (int)(r >> 8);
  }
}

// ---------------- layer kernels ----------------

// layers 1+2a fused, 2 nodes/wave (r10-proven structure).
// Output prescaled + fp16-PACKED: hp16[node][32] (__half2) = rows of 128B.
__global__ void k_l12(const float* __restrict__ xp, const int* __restrict__ offs,
                      const int* __restrict__ srcs, const float* __restrict__ inv_sqrt,
                      const float* __restrict__ W1, const float* __restrict__ b1,
                      const float* __restrict__ W2, __half2* __restrict__ hp16, int n) {
  __shared__ float hrow[4][2][64];
  int tid = threadIdx.x;
  int lane = tid & 63, w = tid >> 6;
  int hl = lane & 31, half = lane >> 5;
  float w1r[5];
#pragma unroll
  for (int k = 0; k < 5; ++k) w1r[k] = W1[k * 64 + lane];
  float bias = b1[lane];
  float wreg[64];
#pragma unroll
  for (int k = 0; k < 64; ++k) wreg[k] = W2[k * 64 + lane];
  float* slotA = &hrow[w][0][0];
  float* slotB = &hrow[w][1][0];
  int wid0 = (blockIdx.x * blockDim.x + tid) >> 6;
  int nw = (gridDim.x * blockDim.x) >> 6;
  for (int i2 = wid0 * 2; i2 < n; i2 += nw * 2) {
    int iA = i2, iB = i2 + 1;
    int node = (half == 0) ? iA : iB;
    bool valid = node < n;
    float a0 = 0.f, a1 = 0.f, a2 = 0.f, a3 = 0.f, a4 = 0.f;
    float isd = 0.f;
    if (valid) {
      isd = inv_sqrt[node];
      int beg = offs[node], end = offs[node + 1];
      for (int j = beg + hl; j < end; j += 32) {
        int s = srcs[j];
        const float* xs = xp + (size_t)s * 5;
        float4 xv = *(const float4*)xs;   // 4B-aligned dwordx4 (HW-legal)
        float x4 = xs[4];
        a0 += xv.x; a1 += xv.y; a2 += xv.z; a3 += xv.w; a4 += x4;
      }
    }
#pragma unroll
    for (int d = 16; d; d >>= 1) {
      a0 += __shfl_xor(a0, d); a1 += __shfl_xor(a1, d); a2 += __shfl_xor(a2, d);
      a3 += __shfl_xor(a3, d); a4 += __shfl_xor(a4, d);
    }
    if (valid) {
      const float* xi = xp + (size_t)node * 5;
      a0 = (a0 + xi[0]) * isd; a1 = (a1 + xi[1]) * isd; a2 = (a2 + xi[2]) * isd;
      a3 = (a3 + xi[3]) * isd; a4 = (a4 + xi[4]) * isd;
    }
    float aA0 = __shfl(a0, hl),      aA1 = __shfl(a1, hl),      aA2 = __shfl(a2, hl);
    float aA3 = __shfl(a3, hl),      aA4 = __shfl(a4, hl);
    float aB0 = __shfl(a0, hl | 32), aB1 = __shfl(a1, hl | 32), aB2 = __shfl(a2, hl | 32);
    float aB3 = __shfl(a3, hl | 32), aB4 = __shfl(a4, hl | 32);
    float isdA = __shfl(isd, 0), isdB = __shfl(isd, 32);
    float hA = bias;
    hA = fmaf(aA0, w1r[0], hA); hA = fmaf(aA1, w1r[1], hA); hA = fmaf(aA2, w1r[2], hA);
    hA = fmaf(aA3, w1r[3], hA); hA = fmaf(aA4, w1r[4], hA);
    hA = fmaxf(hA, 0.f);
    float hB = bias;
    hB = fmaf(aB0, w1r[0], hB); hB = fmaf(aB1, w1r[1], hB); hB = fmaf(aB2, w1r[2], hB);
    hB = fmaf(aB3, w1r[3], hB); hB = fmaf(aB4, w1r[4], hB);
    hB = fmaxf(hB, 0.f);
    slotA[lane] = hA;
    slotB[lane] = hB;
    float ac0 = 0.f, ac1 = 0.f, ac2 = 0.f, ac3 = 0.f;
#pragma unroll
    for (int k4 = 0; k4 < 16; ++k4) {
      float4 hq = *(const float4*)&slotA[k4 * 4];
      ac0 = fmaf(hq.x, wreg[k4 * 4],     ac0);
      ac1 = fmaf(hq.y, wreg[k4 * 4 + 1], ac1);
      ac2 = fmaf(hq.z, wreg[k4 * 4 + 2], ac2);
      ac3 = fmaf(hq.w, wreg[k4 * 4 + 3], ac3);
    }
    float vA = ((ac0 + ac1) + (ac2 + ac3)) * isdA;
    float vAn = __shfl_down(vA, 1);
    if (!(lane & 1)) hp16[(size_t)iA * 32 + (lane >> 1)] = __floats2half2_rn(vA, vAn);
    if (iB < n) {
      float bc0 = 0.f, bc1 = 0.f, bc2 = 0.f, bc3 = 0.f;
#pragma unroll
      for (int k4 = 0; k4 < 16; ++k4) {
        float4 hq = *(const float4*)&slotB[k4 * 4];
        bc0 = fmaf(hq.x, wreg[k4 * 4],     bc0);
        bc1 = fmaf(hq.y, wreg[k4 * 4 + 1], bc1);
        bc2 = fmaf(hq.z, wreg[k4 * 4 + 2], bc2);
        bc3 = fmaf(hq.w, wreg[k4 * 4 + 3], bc3);
      }
      float vB = ((bc0 + bc1) + (bc2 + bc3)) * isdB;
      float vBn = __shfl_down(vB, 1);
      if (!(lane & 1)) hp16[(size_t)iB * 32 + (lane >> 1)] = __floats2half2_rn(vB, vBn);
    }
  }
}

// layers 2b+3a fused on fp16 rows (128B = 1 cache line per edge).
// lane = (slot 0..7, featgroup 0..7): slot owns contiguous run of 4 edges
// (int4 index + 4x16B row loads) -> 32 edges in flight per wave.
__global__ void k_agg64w3(const __half2* __restrict__ hp16, const int* __restrict__ offs,
                          const int* __restrict__ srcs, const float* __restrict__ inv_sqrt,
                          const float* __restrict__ b2, const float* __restrict__ W3,
                          float* __restrict__ h3p, int n) {
  int wid = (blockIdx.x * blockDim.x + threadIdx.x) >> 6;
  int lane = threadIdx.x & 63;
  if (wid >= n) return;
  int slot = lane >> 3;   // edge slot 0..7
  int fl   = lane & 7;    // feature octet: feats fl*8 .. fl*8+7
  float b2r[8], w30[8], w31[8];
#pragma unroll
  for (int q = 0; q < 8; ++q) {
    b2r[q] = b2[fl * 8 + q];
    w30[q] = W3[(fl * 8 + q) * 2];
    w31[q] = W3[(fl * 8 + q) * 2 + 1];
  }
  int beg = offs[wid], end = offs[wid + 1];
  float isd = inv_sqrt[wid];
  float acc[8];
#pragma unroll
  for (int q = 0; q < 8; ++q) acc[q] = 0.f;
  const float* hpf = (const float*)hp16;   // row = 32 floats-worth of half2 = 128B
  int c = beg;
  for (; c + 32 <= end; c += 32) {
    int j = c + (slot << 2);
    int4 sv = *(const int4*)(srcs + j);
    float4 r0 = *(const float4*)(hpf + (size_t)sv.x * 32 + fl * 4);
    float4 r1 = *(const float4*)(hpf + (size_t)sv.y * 32 + fl * 4);
    float4 r2 = *(const float4*)(hpf + (size_t)sv.z * 32 + fl * 4);
    float4 r3 = *(const float4*)(hpf + (size_t)sv.w * 32 + fl * 4);
    const __half2* h0 = (const __half2*)&r0;
    const __half2* h1 = (const __half2*)&r1;
    const __half2* h2_ = (const __half2*)&r2;
    const __half2* h3_ = (const __half2*)&r3;
#pragma unroll
    for (int q = 0; q < 4; ++q) {
      float2 f0 = __half22float2(h0[q]);
      float2 f1 = __half22float2(h1[q]);
      float2 f2 = __half22float2(h2_[q]);
      float2 f3 = __half22float2(h3_[q]);
      acc[q * 2]     += (f0.x + f1.x) + (f2.x + f3.x);
      acc[q * 2 + 1] += (f0.y + f1.y) + (f2.y + f3.y);
    }
  }
  {
    int j0 = c + (slot << 2);
    int je = min(j0 + 4, end);
    for (int j = j0; j < je; ++j) {
      int s = srcs[j];
      float4 r0 = *(const float4*)(hpf + (size_t)s * 32 + fl * 4);
      const __half2* h0 = (const __half2*)&r0;
#pragma unroll
      for (int q = 0; q < 4; ++q) {
        float2 f0 = __half22float2(h0[q]);
        acc[q * 2] += f0.x; acc[q * 2 + 1] += f0.y;
      }
    }
  }
  // reduce over the 8 edge slots (xor flips slot bits)
#pragma unroll
  for (int q = 0; q < 8; ++q) {
    acc[q] += __shfl_xor(acc[q], 8);
    acc[q] += __shfl_xor(acc[q], 16);
    acc[q] += __shfl_xor(acc[q], 32);
  }
  // self row (prescaled, quantized)
  {
    float4 r0 = *(const float4*)(hpf + (size_t)wid * 32 + fl * 4);
    const __half2* h0 = (const __half2*)&r0;
#pragma unroll
    for (int q = 0; q < 4; ++q) {
      float2 f0 = __half22float2(h0[q]);
      acc[q * 2] += f0.x; acc[q * 2 + 1] += f0.y;
    }
  }
  float p0 = 0.f, p1 = 0.f;
#pragma unroll
  for (int q = 0; q < 8; ++q) {
    float h2v = fmaxf(fmaf(isd, acc[q], b2r[q]), 0.f);
    p0 = fmaf(h2v, w30[q], p0);
    p1 = fmaf(h2v, w31[q], p1);
  }
  // reduce over the 8 feature octets (xor flips fl bits)
  p0 += __shfl_xor(p0, 1); p1 += __shfl_xor(p1, 1);
  p0 += __shfl_xor(p0, 2); p1 += __shfl_xor(p1, 2);
  p0 += __shfl_xor(p0, 4); p1 += __shfl_xor(p1, 4);
  if (lane == 0) {
    h3p[(size_t)wid * 2]     = p0 * isd;
    h3p[(size_t)wid * 2 + 1] = p1 * isd;
  }
}

// out = isd*(sum h3p[src] + h3p[self]) + b3  — TWO nodes per wave (32-lane halves)
__global__ void k_agg2(const float* __restrict__ h3p, const int* __restrict__ offs,
                       const int* __restrict__ srcs, const float* __restrict__ inv_sqrt,
                       const float* __restrict__ b3, float* __restrict__ out, int n) {
  int wv = (blockIdx.x * blockDim.x + threadIdx.x) >> 6;
  int lane = threadIdx.x & 63;
  int half = lane >> 5, hl = lane & 31;
  int node = wv * 2 + half;
  float a0 = 0.f, a1 = 0.f;
  if (node < n) {
    int beg = offs[node], end = offs[node + 1];
    for (int j = beg + hl; j < end; j += 32) {
      int s = srcs[j];
      float2 hv = *(const float2*)(h3p + (size_t)s * 2);
      a0 += hv.x; a1 += hv.y;
    }
  }
#pragma unroll
  for (int d = 16; d; d >>= 1) { a0 += __shfl_xor(a0, d); a1 += __shfl_xor(a1, d); }
  if (node < n && hl == 0) {
    float isd = inv_sqrt[node];
    float2 self = *(const float2*)(h3p + (size_t)node * 2);
    out[(size_t)node * 2]     = fmaf(isd, a0 + self.x, b3[0]);
    out[(size_t)node * 2 + 1] = fmaf(isd, a1 + self.y, b3[1]);
  }
}

// ---------------- launcher ----------------

extern "C" void kernel_launch(void* const* d_in, const int* in_sizes, int n_in,
                              void* d_out, int out_size, void* d_ws, size_t ws_size,
                              hipStream_t stream) {
  const float* x  = (const float*)d_in[0];
  const int*   ei = (const int*)d_in[1];
  const float* W1 = (const float*)d_in[2];
  const float* b1 = (const float*)d_in[3];
  const float* W2 = (const float*)d_in[4];
  const float* b2 = (const float*)d_in[5];
  const float* W3 = (const float*)d_in[6];
  const float* b3 = (const float*)d_in[7];
  float* out = (float*)d_out;

  const int N = in_sizes[0] / 5;
  const int E = in_sizes[1] / 2;
  const int* src = ei;
  const int* dst = ei + E;

  const int NB = (N + 255) >> 8;
  const int chunk = (E + CB - 1) / CB;
  const int n2 = NB * CB;
  const int nb2 = (n2 + 1023) / 1024;   // <= 256

  char* p = (char*)d_ws;
  auto alloc = [&](size_t bytes) {
    char* r = p;
    p += (bytes + 255) & ~(size_t)255;
    return r;
  };
  int*      histG     = (int*)alloc((size_t)n2 * 4);
  int*      histS     = (int*)alloc((size_t)n2 * 4);
  int*      blockSums = (int*)alloc((size_t)nb2 * 4);
  int*      blockOffs = (int*)alloc((size_t)(nb2 + 1) * 4);
  unsigned* recs      = (unsigned*)alloc((size_t)E * 4);
  int*      srcs      = (int*)alloc((size_t)E * 4);
  int*      offs      = (int*)alloc((size_t)(N + 1) * 4);
  float*    inv_sqrt  = (float*)alloc((size_t)N * 4);
  float*    xp        = (float*)alloc((size_t)N * 5 * 4);
  __half2*  hp16      = (__half2*)alloc((size_t)N * 32 * 4);
  float*    h3p       = (float*)alloc((size_t)N * 2 * 4);

  const int wavesBlocks = (N * 64 + 255) / 256;       // one wave per node
  const int pairs = (N + 1) / 2;
  const int pairBlocks = (pairs * 64 + 255) / 256;    // one wave per 2 nodes

  // CSR build via stable bucket sort — zero global atomics
  k_hist<<<CB, 256, 0, stream>>>(dst, histG, E, NB, chunk);
  k_scan_local<<<nb2, 1024, 0, stream>>>(histG, histS, blockSums, n2);
  k_scan_blocks<<<1, 256, 0, stream>>>(blockSums, blockOffs, nb2);
  k_scatter<<<CB, 256, 0, stream>>>(src, dst, histS, blockOffs, recs, E, NB, chunk);
  k_build<<<NB, 256, 0, stream>>>(recs, histS, blockOffs, x, offs, inv_sqrt, xp, srcs, N, NB, E);

  // layers 1+2a fused: hp16[node][32] (__half2) = ((relu((A x)W1+b1) @ W2) * isd) packed
  k_l12<<<2048, 256, 0, stream>>>(xp, offs, srcs, inv_sqrt, W1, b1, W2, hp16, N);
  // layers 2b+3a fused on fp16 rows
  k_agg64w3<<<wavesBlocks, 256, 0, stream>>>(hp16, offs, srcs, inv_sqrt, b2, W3, h3p, N);
  // layer 3 aggregation (2 nodes/wave)
  k_agg2<<<pairBlocks, 256, 0, stream>>>(h3p, offs, srcs, inv_sqrt, b3, out, N);
}